// Round 4
// baseline (524.548 us; speedup 1.0000x reference)
//
#include <hip/hip_runtime.h>
#include <hip/hip_bf16.h>

// ---------------------------------------------------------------------------
// EdgeClassifier: 2x GCNConv + edge MLP.
//   CSR build -> (nodemm + agg) x2 -> MFMA edge MLP (both layers MFMA).
// h2 stored bf16; Wc1/Wc2 pre-converted to bf16 (transposed / zero-padded);
// edge-MLP layer2 uses XOR-swizzled bf16 LDS tile.
// ---------------------------------------------------------------------------

typedef __attribute__((ext_vector_type(8))) short  bf16x8;
typedef __attribute__((ext_vector_type(16))) float f32x16;

__device__ inline short f2bf(float f)
{
    union { float f; unsigned u; } v; v.f = f;
    unsigned r = v.u + 0x7fff + ((v.u >> 16) & 1);   // RNE
    return (short)(r >> 16);
}

// ---------------- CSR build ----------------
__global__ __launch_bounds__(256) void k_hist(const int* __restrict__ ei, int* __restrict__ degcnt, int E)
{
    int e = blockIdx.x * 256 + threadIdx.x;
    if (e < E) atomicAdd(&degcnt[ei[E + e]], 1);
}

__global__ __launch_bounds__(256) void k_dinv(const int* __restrict__ degcnt, float* __restrict__ dinv, int n)
{
    int v = blockIdx.x * 256 + threadIdx.x;
    if (v < n) dinv[v] = rsqrtf((float)(degcnt[v] + 1));
}

__global__ __launch_bounds__(256) void k_bsum(const int* __restrict__ deg, int n, int* __restrict__ bsum)
{
    __shared__ int s[256];
    int t = threadIdx.x;
    int i = blockIdx.x * 256 + t;
    s[t] = (i < n) ? deg[i] : 0;
    __syncthreads();
    for (int o = 128; o > 0; o >>= 1) {
        if (t < o) s[t] += s[t + o];
        __syncthreads();
    }
    if (t == 0) bsum[blockIdx.x] = s[0];
}

__global__ __launch_bounds__(512) void k_boff(const int* __restrict__ bsum, int nb, int* __restrict__ boff)
{
    __shared__ int s[512];
    int t = threadIdx.x;
    int v = (t < nb) ? bsum[t] : 0;
    s[t] = v;
    __syncthreads();
    for (int o = 1; o < 512; o <<= 1) {
        int a = (t >= o) ? s[t - o] : 0;
        __syncthreads();
        s[t] += a;
        __syncthreads();
    }
    if (t < nb) boff[t] = s[t] - v;
}

__global__ __launch_bounds__(256) void k_rowstart(const int* __restrict__ deg, const int* __restrict__ boff,
                                                  int* __restrict__ rs, int n, int total)
{
    __shared__ int s[256];
    int t = threadIdx.x;
    int i = blockIdx.x * 256 + t;
    int v = (i < n) ? deg[i] : 0;
    s[t] = v;
    __syncthreads();
    for (int o = 1; o < 256; o <<= 1) {
        int a = (t >= o) ? s[t - o] : 0;
        __syncthreads();
        s[t] += a;
        __syncthreads();
    }
    if (i < n) rs[i] = boff[blockIdx.x] + s[t] - v;
    if (i == 0) rs[n] = total;
}

__global__ __launch_bounds__(256) void k_scatter(const int* __restrict__ ei, const int* __restrict__ rs,
                                                 int* __restrict__ cursor, int* __restrict__ col, int E)
{
    int e = blockIdx.x * 256 + threadIdx.x;
    if (e < E) {
        int d = ei[E + e];
        int pos = atomicAdd(&cursor[d], 1);
        col[rs[d] + pos] = ei[e];
    }
}

// ---------------- weight prep: Wc1T[j][144] bf16, Wc2T[32][64] bf16 (padded) ----------------
__global__ __launch_bounds__(256) void k_prep(const float* __restrict__ Wc1, const float* __restrict__ Wc2,
                                              short* __restrict__ Wc1T, short* __restrict__ Wc2T)
{
    int t = blockIdx.x * 256 + threadIdx.x;
    if (t < 9216) {                       // Wc1T[j*144+k] = bf(Wc1[k*64+j])
        int j = t / 144, k = t - j * 144;
        Wc1T[t] = f2bf(Wc1[k * 64 + j]);
    }
    int u = t - 9216;
    if (u >= 0 && u < 2048) {             // Wc2T[r*64+k] = r<5 ? bf(Wc2[k*5+r]) : 0
        int rr = u / 64, k = u - rr * 64;
        Wc2T[u] = (rr < 5) ? f2bf(Wc2[k * 5 + rr]) : (short)0;
    }
}

// ---------------- per-node GEMM: hsc[v][j] = dinv[v] * sum_k in[v][k]*W[k][j] ----------------
template <int DIN>
__global__ __launch_bounds__(256) void k_nodemm(const float* __restrict__ in, const float* __restrict__ W,
                                                const float* __restrict__ dinv, float* __restrict__ out, int n)
{
    int lane = threadIdx.x & 63;
    int v = __builtin_amdgcn_readfirstlane(blockIdx.x * 4 + (threadIdx.x >> 6));
    if (v >= n) return;
    const float* row = &in[(size_t)v * DIN];
    float acc = 0.f;
#pragma unroll
    for (int k = 0; k < DIN; ++k) acc = fmaf(row[k], W[k * 64 + lane], acc);
    out[(size_t)v * 64 + lane] = acc * dinv[v];
}

// ---------------- aggregation: out[v][j] = f(dinv[v]*(self + sum_nb hsc) + b[j]) ----------------
// wave per node; 64 neighbor indices loaded in one coalesced vector load,
// broadcast via v_readlane (no scalar-load chain), 4 gathers in flight.
template <int RELU, typename OUT>
__global__ __launch_bounds__(256) void k_agg(const float* __restrict__ hsc, const float* __restrict__ dinv,
                                             const int* __restrict__ rs, const int* __restrict__ col,
                                             const float* __restrict__ bias, OUT* __restrict__ out, int n)
{
    int lane = threadIdx.x & 63;
    int v = __builtin_amdgcn_readfirstlane(blockIdx.x * 4 + (threadIdx.x >> 6));
    if (v >= n) return;
    float acc = hsc[(size_t)v * 64 + lane];   // self loop
    int i = rs[v];
    const int end = rs[v + 1];
    while (i < end) {
        int cnt = end - i;
        if (cnt > 64) cnt = 64;
        int cl = col[i + (lane < cnt ? lane : cnt - 1)];
        int k = 0;
        for (; k + 4 <= cnt; k += 4) {
            int s0 = __builtin_amdgcn_readlane(cl, k);
            int s1 = __builtin_amdgcn_readlane(cl, k + 1);
            int s2 = __builtin_amdgcn_readlane(cl, k + 2);
            int s3 = __builtin_amdgcn_readlane(cl, k + 3);
            float a0 = hsc[(size_t)s0 * 64 + lane];
            float a1 = hsc[(size_t)s1 * 64 + lane];
            float a2 = hsc[(size_t)s2 * 64 + lane];
            float a3 = hsc[(size_t)s3 * 64 + lane];
            acc += a0; acc += a1; acc += a2; acc += a3;
        }
        for (; k < cnt; ++k) {
            int s = __builtin_amdgcn_readlane(cl, k);
            acc += hsc[(size_t)s * 64 + lane];
        }
        i += cnt;
    }
    float rv = dinv[v] * acc + bias[lane];
    if (RELU) rv = rv > 0.f ? rv : 0.f;
    if constexpr (sizeof(OUT) == 2)
        out[(size_t)v * 64 + lane] = f2bf(rv);
    else
        out[(size_t)v * 64 + lane] = rv;
}

// ---------------- MFMA edge MLP (both layers) ----------------
// Block = 256 thr = 4 waves; wave owns 32 edges.
// L1: D[32e][64h] = A[32x144]@Wc1 (9 ksteps), A gathered from bf16 h2 + f32 attr.
// hid -> bf16 LDS [128][64], XOR-swizzled (byte ^= (row&7)<<4 on 16B slots).
// L2: D[32e][32c(5 used)] = hid[32x64]@Wc2T (4 ksteps). Biases in MFMA C-init.
// Frag maps (verified r2/r3): A row=lane&31,k=(lane>>5)*8+i; B col=lane&31;
// C/D col=lane&31, row=(reg&3)+8*(reg>>2)+4*(lane>>5).
__global__ __launch_bounds__(256) void k_edge_mlp_mfma(
    const short* __restrict__ h2bf, const float* __restrict__ eattr,
    const int* __restrict__ ei,
    const short* __restrict__ Wc1T, const float* __restrict__ bc1,
    const short* __restrict__ Wc2T, const float* __restrict__ bc2,
    float* __restrict__ out, int E)
{
    __shared__ short hid[128 * 64];   // 16 KB, swizzled

    const int tid  = threadIdx.x;
    const int w    = tid >> 6;
    const int lane = tid & 63;
    const int r    = lane & 31;
    const int kg   = lane >> 5;

    // B fragments (bf16, 16B loads)
    bf16x8 b1f[9][2];
#pragma unroll
    for (int t = 0; t < 9; ++t) {
#pragma unroll
        for (int nt = 0; nt < 2; ++nt)
            b1f[t][nt] = *(const bf16x8*)&Wc1T[(r + nt * 32) * 144 + t * 16 + kg * 8];
    }
    bf16x8 b2f[4];
#pragma unroll
    for (int t2 = 0; t2 < 4; ++t2)
        b2f[t2] = *(const bf16x8*)&Wc2T[r * 64 + t2 * 16 + kg * 8];

    const float bias0 = bc1[r];
    const float bias1 = bc1[r + 32];
    const float bias2 = (r < 5) ? bc2[r] : 0.f;

    // ---- layer 1: gather + MFMA ----
    const long eb = (long)blockIdx.x * 128 + w * 32;
    long e = eb + r;
    if (e >= E) e = E - 1;                 // clamp; tail rows never stored
    const int s = ei[e];
    const int d = ei[E + e];
    const short* srow = &h2bf[(size_t)s * 64];
    const short* drow = &h2bf[(size_t)d * 64];
    const float* arow = &eattr[(size_t)e * 16];

    f32x16 acc0, acc1;
#pragma unroll
    for (int i = 0; i < 16; ++i) { acc0[i] = bias0; acc1[i] = bias1; }

#pragma unroll
    for (int t = 0; t < 8; ++t) {
        const short* src = (t < 4) ? &srow[t * 16 + kg * 8] : &drow[(t - 4) * 16 + kg * 8];
        bf16x8 a = *(const bf16x8*)src;
        acc0 = __builtin_amdgcn_mfma_f32_32x32x16_bf16(a, b1f[t][0], acc0, 0, 0, 0);
        acc1 = __builtin_amdgcn_mfma_f32_32x32x16_bf16(a, b1f[t][1], acc1, 0, 0, 0);
    }
    {   // t = 8: edge_attr (f32 -> bf16)
        float4 lo = *(const float4*)&arow[kg * 8];
        float4 hi = *(const float4*)&arow[kg * 8 + 4];
        bf16x8 a;
        a[0] = f2bf(lo.x); a[1] = f2bf(lo.y); a[2] = f2bf(lo.z); a[3] = f2bf(lo.w);
        a[4] = f2bf(hi.x); a[5] = f2bf(hi.y); a[6] = f2bf(hi.z); a[7] = f2bf(hi.w);
        acc0 = __builtin_amdgcn_mfma_f32_32x32x16_bf16(a, b1f[8][0], acc0, 0, 0, 0);
        acc1 = __builtin_amdgcn_mfma_f32_32x32x16_bf16(a, b1f[8][1], acc1, 0, 0, 0);
    }

    // ---- epilogue 1: relu -> bf16 -> swizzled LDS ----
#pragma unroll
    for (int reg = 0; reg < 16; ++reg) {
        const int row = (reg & 3) + 8 * (reg >> 2) + 4 * kg;   // 0..31
        const int gr  = w * 32 + row;
        const int sw  = (gr & 7) << 4;                         // byte swizzle
        float v0 = acc0[reg]; v0 = v0 > 0.f ? v0 : 0.f;
        float v1 = acc1[reg]; v1 = v1 > 0.f ? v1 : 0.f;
        hid[gr * 64 + ((((r)      << 1) ^ sw) >> 1)] = f2bf(v0);
        hid[gr * 64 + ((((r + 32) << 1) ^ sw) >> 1)] = f2bf(v1);
    }
    __syncthreads();

    // ---- layer 2: LDS -> MFMA ----
    const int gr2 = w * 32 + r;            // this lane's edge row
    const int sw2 = (gr2 & 7) << 4;
    f32x16 acc2;
#pragma unroll
    for (int i = 0; i < 16; ++i) acc2[i] = bias2;
#pragma unroll
    for (int t2 = 0; t2 < 4; ++t2) {
        const int boff = (t2 * 32 + kg * 16) ^ sw2;            // 16B-aligned
        bf16x8 a = *(const bf16x8*)((const char*)&hid[gr2 * 64] + boff);
        acc2 = __builtin_amdgcn_mfma_f32_32x32x16_bf16(a, b2f[t2], acc2, 0, 0, 0);
    }

    // ---- epilogue 2: store (lanes r<5 hold classes) ----
#pragma unroll
    for (int reg = 0; reg < 16; ++reg) {
        const int row = (reg & 3) + 8 * (reg >> 2) + 4 * kg;
        const long eo = eb + row;
        if (r < 5 && eo < E) out[(size_t)eo * 5 + r] = acc2[reg];
    }
}

extern "C" void kernel_launch(void* const* d_in, const int* in_sizes, int n_in,
                              void* d_out, int out_size, void* d_ws, size_t ws_size,
                              hipStream_t stream)
{
    const float* x     = (const float*)d_in[0];
    const int*   ei    = (const int*)d_in[1];
    const float* eattr = (const float*)d_in[2];
    const float* W1    = (const float*)d_in[3];
    const float* b1    = (const float*)d_in[4];
    const float* W2    = (const float*)d_in[5];
    const float* b2    = (const float*)d_in[6];
    const float* Wc1   = (const float*)d_in[7];
    const float* bc1   = (const float*)d_in[8];
    const float* Wc2   = (const float*)d_in[9];
    const float* bc2   = (const float*)d_in[10];
    float* outp = (float*)d_out;

    const int N = in_sizes[0] / 32;
    const int E = in_sizes[1] / 2;

    // ---- carve workspace (~46 MB) ----
    size_t off = 0;
    char* base = (char*)d_ws;
    auto carve = [&](size_t bytes) -> void* {
        void* p = base + off;
        off += (bytes + 255) & ~(size_t)255;
        return p;
    };
    int*   degcnt = (int*)carve((size_t)2 * N * 4);
    int*   cursor = degcnt + N;
    float* dinv   = (float*)carve((size_t)N * 4);
    int*   rs     = (int*)carve((size_t)(N + 1) * 4);
    int*   bsum   = (int*)carve(512 * 4);
    int*   boff   = (int*)carve(512 * 4);
    int*   col    = (int*)carve((size_t)E * 4);
    float* bufB   = (float*)carve((size_t)N * 64 * 4);
    short* h2bf   = (short*)carve((size_t)N * 64 * 2);
    short* Wc1T   = (short*)carve(9216 * 2);
    short* Wc2T   = (short*)carve(2048 * 2);
    float* bufA   = outp;   // alias d_out: dead before edge MLP writes it
    (void)ws_size; (void)n_in; (void)out_size;

    const int NB = (N + 255) / 256;
    const int EB = (E + 255) / 256;
    const int NV = (N + 3) / 4;
    const int MB = (E + 127) / 128;

    hipMemsetAsync(degcnt, 0, (size_t)2 * N * 4, stream);

    k_prep<<<(9216 + 2048 + 255) / 256, 256, 0, stream>>>(Wc1, Wc2, Wc1T, Wc2T);
    k_hist<<<EB, 256, 0, stream>>>(ei, degcnt, E);
    k_dinv<<<NB, 256, 0, stream>>>(degcnt, dinv, N);
    k_bsum<<<NB, 256, 0, stream>>>(degcnt, N, bsum);
    k_boff<<<1, 512, 0, stream>>>(bsum, NB, boff);
    k_rowstart<<<NB, 256, 0, stream>>>(degcnt, boff, rs, N, E);
    k_scatter<<<EB, 256, 0, stream>>>(ei, rs, cursor, col, E);

    // layer 1
    k_nodemm<32><<<NV, 256, 0, stream>>>(x, W1, dinv, bufA, N);
    k_agg<1, float><<<NV, 256, 0, stream>>>(bufA, dinv, rs, col, b1, bufB, N);
    // layer 2 (h2 stored bf16)
    k_nodemm<64><<<NV, 256, 0, stream>>>(bufB, W2, dinv, bufA, N);
    k_agg<0, short><<<NV, 256, 0, stream>>>(bufA, dinv, rs, col, b2, h2bf, N);
    // edge MLP (all-MFMA)
    k_edge_mlp_mfma<<<MB, 256, 0, stream>>>(h2bf, eattr, ei, Wc1T, bc1, Wc2T, bc2, outp, E);
}

// Round 5
// 459.051 us; speedup vs baseline: 1.1427x; 1.1427x over previous
//
#include <hip/hip_runtime.h>
#include <hip/hip_bf16.h>

// ---------------------------------------------------------------------------
// EdgeClassifier: 2x GCNConv + edge MLP.
// All node-feature intermediates in bf16 (halves gather traffic):
//   nodemm32 (VALU, f32 x @ W1 -> bf16 hsc) -> agg_bf (bf16 gather, 2 nodes/wave)
//   -> nodemm64_mfma (bf16 MFMA) -> agg_bf -> h2 bf16 -> all-MFMA edge MLP.
// ---------------------------------------------------------------------------

typedef __attribute__((ext_vector_type(8))) short  bf16x8;
typedef __attribute__((ext_vector_type(16))) float f32x16;

__device__ inline short f2bf(float f)
{
    union { float f; unsigned u; } v; v.f = f;
    unsigned r = v.u + 0x7fff + ((v.u >> 16) & 1);   // RNE
    return (short)(r >> 16);
}

__device__ inline float2 bfp2f(unsigned u)
{
    union { unsigned u; float f; } a, b;
    a.u = u << 16;            // low short  -> even channel
    b.u = u & 0xffff0000u;    // high short -> odd channel
    return make_float2(a.f, b.f);
}

// ---------------- CSR build ----------------
__global__ __launch_bounds__(256) void k_hist(const int* __restrict__ ei, int* __restrict__ degcnt, int E)
{
    int e = blockIdx.x * 256 + threadIdx.x;
    if (e < E) atomicAdd(&degcnt[ei[E + e]], 1);
}

__global__ __launch_bounds__(256) void k_dinv(const int* __restrict__ degcnt, float* __restrict__ dinv, int n)
{
    int v = blockIdx.x * 256 + threadIdx.x;
    if (v < n) dinv[v] = rsqrtf((float)(degcnt[v] + 1));
}

__global__ __launch_bounds__(256) void k_bsum(const int* __restrict__ deg, int n, int* __restrict__ bsum)
{
    __shared__ int s[256];
    int t = threadIdx.x;
    int i = blockIdx.x * 256 + t;
    s[t] = (i < n) ? deg[i] : 0;
    __syncthreads();
    for (int o = 128; o > 0; o >>= 1) {
        if (t < o) s[t] += s[t + o];
        __syncthreads();
    }
    if (t == 0) bsum[blockIdx.x] = s[0];
}

__global__ __launch_bounds__(512) void k_boff(const int* __restrict__ bsum, int nb, int* __restrict__ boff)
{
    __shared__ int s[512];
    int t = threadIdx.x;
    int v = (t < nb) ? bsum[t] : 0;
    s[t] = v;
    __syncthreads();
    for (int o = 1; o < 512; o <<= 1) {
        int a = (t >= o) ? s[t - o] : 0;
        __syncthreads();
        s[t] += a;
        __syncthreads();
    }
    if (t < nb) boff[t] = s[t] - v;
}

__global__ __launch_bounds__(256) void k_rowstart(const int* __restrict__ deg, const int* __restrict__ boff,
                                                  int* __restrict__ rs, int n, int total)
{
    __shared__ int s[256];
    int t = threadIdx.x;
    int i = blockIdx.x * 256 + t;
    int v = (i < n) ? deg[i] : 0;
    s[t] = v;
    __syncthreads();
    for (int o = 1; o < 256; o <<= 1) {
        int a = (t >= o) ? s[t - o] : 0;
        __syncthreads();
        s[t] += a;
        __syncthreads();
    }
    if (i < n) rs[i] = boff[blockIdx.x] + s[t] - v;
    if (i == 0) rs[n] = total;
}

__global__ __launch_bounds__(256) void k_scatter(const int* __restrict__ ei, const int* __restrict__ rs,
                                                 int* __restrict__ cursor, int* __restrict__ col, int E)
{
    int e = blockIdx.x * 256 + threadIdx.x;
    if (e < E) {
        int d = ei[E + e];
        int pos = atomicAdd(&cursor[d], 1);
        col[rs[d] + pos] = ei[e];
    }
}

// ---------------- weight prep ----------------
// Wc1T[j][144], Wc2T[32][64] (zero-padded classes), W2T[j][64]  (all bf16)
__global__ __launch_bounds__(256) void k_prep(const float* __restrict__ Wc1, const float* __restrict__ Wc2,
                                              const float* __restrict__ W2,
                                              short* __restrict__ Wc1T, short* __restrict__ Wc2T,
                                              short* __restrict__ W2T)
{
    int t = blockIdx.x * 256 + threadIdx.x;
    if (t < 9216) {
        int j = t / 144, k = t - j * 144;
        Wc1T[t] = f2bf(Wc1[k * 64 + j]);
    } else if (t < 11264) {
        int u = t - 9216;
        int rr = u / 64, k = u - rr * 64;
        Wc2T[u] = (rr < 5) ? f2bf(Wc2[k * 5 + rr]) : (short)0;
    } else if (t < 15360) {
        int u = t - 11264;
        int j = u / 64, k = u - j * 64;
        W2T[u] = f2bf(W2[k * 64 + j]);
    }
}

// ---------------- layer-1 per-node GEMM (f32 VALU): hsc = (x@W1)*dinv, bf16 out ----------------
__global__ __launch_bounds__(256) void k_nodemm32(const float* __restrict__ in, const float* __restrict__ W,
                                                  const float* __restrict__ dinv, unsigned short* __restrict__ out, int n)
{
    int lane = threadIdx.x & 63;
    int v = __builtin_amdgcn_readfirstlane(blockIdx.x * 4 + (threadIdx.x >> 6));
    if (v >= n) return;
    const float* row = &in[(size_t)v * 32];
    float acc = 0.f;
#pragma unroll
    for (int k = 0; k < 32; ++k) acc = fmaf(row[k], W[k * 64 + lane], acc);
    out[(size_t)v * 64 + lane] = (unsigned short)f2bf(acc * dinv[v]);
}

// ---------------- layer-2 per-node GEMM (MFMA): hsc2 = (h1@W2)*dinv, bf16 ----------------
// wave = 32 nodes; A row=lane&31 (node), k=(lane>>5)*8+i; B col=lane&31 (j).
__global__ __launch_bounds__(256) void k_nodemm64_mfma(const unsigned short* __restrict__ h1,
                                                       const short* __restrict__ W2T,
                                                       const float* __restrict__ dinv,
                                                       unsigned short* __restrict__ out, int n)
{
    const int tid  = threadIdx.x;
    const int w    = tid >> 6;
    const int lane = tid & 63;
    const int r    = lane & 31;
    const int kg   = lane >> 5;
    const int nb   = blockIdx.x * 128 + w * 32;

    bf16x8 bf[4][2];
#pragma unroll
    for (int t = 0; t < 4; ++t) {
#pragma unroll
        for (int nt = 0; nt < 2; ++nt)
            bf[t][nt] = *(const bf16x8*)&W2T[(r + nt * 32) * 64 + t * 16 + kg * 8];
    }

    int row = nb + r;
    if (row >= n) row = n - 1;            // clamp; tail never stored
    f32x16 acc0 = {0.f}, acc1 = {0.f};
#pragma unroll
    for (int t = 0; t < 4; ++t) {
        bf16x8 a = *(const bf16x8*)&h1[(size_t)row * 64 + t * 16 + kg * 8];
        acc0 = __builtin_amdgcn_mfma_f32_32x32x16_bf16(a, bf[t][0], acc0, 0, 0, 0);
        acc1 = __builtin_amdgcn_mfma_f32_32x32x16_bf16(a, bf[t][1], acc1, 0, 0, 0);
    }

#pragma unroll
    for (int reg = 0; reg < 16; ++reg) {
        const int nrow = (reg & 3) + 8 * (reg >> 2) + 4 * kg;
        const int node = nb + nrow;
        if (node < n) {
            const float dv = dinv[node];
            out[(size_t)node * 64 + r]      = (unsigned short)f2bf(acc0[reg] * dv);
            out[(size_t)node * 64 + r + 32] = (unsigned short)f2bf(acc1[reg] * dv);
        }
    }
}

// ---------------- aggregation (bf16): out[v][:] = f(dinv[v]*(self+sum_nb) + b) ----------------
// 2 nodes per wave, 32 lanes per node, bf16x2 per lane (128 B coalesced rows).
template <int RELU>
__global__ __launch_bounds__(256) void k_agg_bf(const unsigned short* __restrict__ hsc,
                                                const float* __restrict__ dinv,
                                                const int* __restrict__ rs, const int* __restrict__ col,
                                                const float* __restrict__ bias,
                                                unsigned short* __restrict__ out, int n)
{
    const int tid = threadIdx.x;
    const int l   = tid & 31;
    const int v   = blockIdx.x * 8 + (tid >> 5);
    if (v >= n) return;

    float2 acc = bfp2f(*(const unsigned*)(hsc + (size_t)v * 64 + l * 2));   // self
    int i = rs[v];
    const int end = rs[v + 1];
    for (; i + 4 <= end; i += 4) {
        int c0 = col[i], c1 = col[i + 1], c2 = col[i + 2], c3 = col[i + 3];
        unsigned u0 = *(const unsigned*)(hsc + (size_t)c0 * 64 + l * 2);
        unsigned u1 = *(const unsigned*)(hsc + (size_t)c1 * 64 + l * 2);
        unsigned u2 = *(const unsigned*)(hsc + (size_t)c2 * 64 + l * 2);
        unsigned u3 = *(const unsigned*)(hsc + (size_t)c3 * 64 + l * 2);
        float2 a0 = bfp2f(u0), a1 = bfp2f(u1), a2 = bfp2f(u2), a3 = bfp2f(u3);
        acc.x += a0.x + a1.x + a2.x + a3.x;
        acc.y += a0.y + a1.y + a2.y + a3.y;
    }
    for (; i < end; ++i) {
        float2 a = bfp2f(*(const unsigned*)(hsc + (size_t)col[i] * 64 + l * 2));
        acc.x += a.x; acc.y += a.y;
    }
    const float dv = dinv[v];
    float r0 = fmaf(dv, acc.x, bias[l * 2]);
    float r1 = fmaf(dv, acc.y, bias[l * 2 + 1]);
    if (RELU) { r0 = r0 > 0.f ? r0 : 0.f; r1 = r1 > 0.f ? r1 : 0.f; }
    unsigned o = (unsigned)(unsigned short)f2bf(r0) | ((unsigned)(unsigned short)f2bf(r1) << 16);
    *(unsigned*)(out + (size_t)v * 64 + l * 2) = o;
}

// ---------------- MFMA edge MLP (both layers, unchanged from R4) ----------------
__global__ __launch_bounds__(256) void k_edge_mlp_mfma(
    const unsigned short* __restrict__ h2bf, const float* __restrict__ eattr,
    const int* __restrict__ ei,
    const short* __restrict__ Wc1T, const float* __restrict__ bc1,
    const short* __restrict__ Wc2T, const float* __restrict__ bc2,
    float* __restrict__ out, int E)
{
    __shared__ short hid[128 * 64];   // 16 KB, XOR-swizzled

    const int tid  = threadIdx.x;
    const int w    = tid >> 6;
    const int lane = tid & 63;
    const int r    = lane & 31;
    const int kg   = lane >> 5;

    bf16x8 b1f[9][2];
#pragma unroll
    for (int t = 0; t < 9; ++t) {
#pragma unroll
        for (int nt = 0; nt < 2; ++nt)
            b1f[t][nt] = *(const bf16x8*)&Wc1T[(r + nt * 32) * 144 + t * 16 + kg * 8];
    }
    bf16x8 b2f[4];
#pragma unroll
    for (int t2 = 0; t2 < 4; ++t2)
        b2f[t2] = *(const bf16x8*)&Wc2T[r * 64 + t2 * 16 + kg * 8];

    const float bias0 = bc1[r];
    const float bias1 = bc1[r + 32];
    const float bias2 = (r < 5) ? bc2[r] : 0.f;

    const long eb = (long)blockIdx.x * 128 + w * 32;
    long e = eb + r;
    if (e >= E) e = E - 1;
    const int s = ei[e];
    const int d = ei[E + e];
    const unsigned short* srow = &h2bf[(size_t)s * 64];
    const unsigned short* drow = &h2bf[(size_t)d * 64];
    const float* arow = &eattr[(size_t)e * 16];

    f32x16 acc0, acc1;
#pragma unroll
    for (int i = 0; i < 16; ++i) { acc0[i] = bias0; acc1[i] = bias1; }

#pragma unroll
    for (int t = 0; t < 8; ++t) {
        const unsigned short* src = (t < 4) ? &srow[t * 16 + kg * 8] : &drow[(t - 4) * 16 + kg * 8];
        bf16x8 a = *(const bf16x8*)src;
        acc0 = __builtin_amdgcn_mfma_f32_32x32x16_bf16(a, b1f[t][0], acc0, 0, 0, 0);
        acc1 = __builtin_amdgcn_mfma_f32_32x32x16_bf16(a, b1f[t][1], acc1, 0, 0, 0);
    }
    {
        float4 lo = *(const float4*)&arow[kg * 8];
        float4 hi = *(const float4*)&arow[kg * 8 + 4];
        bf16x8 a;
        a[0] = f2bf(lo.x); a[1] = f2bf(lo.y); a[2] = f2bf(lo.z); a[3] = f2bf(lo.w);
        a[4] = f2bf(hi.x); a[5] = f2bf(hi.y); a[6] = f2bf(hi.z); a[7] = f2bf(hi.w);
        acc0 = __builtin_amdgcn_mfma_f32_32x32x16_bf16(a, b1f[8][0], acc0, 0, 0, 0);
        acc1 = __builtin_amdgcn_mfma_f32_32x32x16_bf16(a, b1f[8][1], acc1, 0, 0, 0);
    }

#pragma unroll
    for (int reg = 0; reg < 16; ++reg) {
        const int row = (reg & 3) + 8 * (reg >> 2) + 4 * kg;
        const int gr  = w * 32 + row;
        const int sw  = (gr & 7) << 4;
        float v0 = acc0[reg]; v0 = v0 > 0.f ? v0 : 0.f;
        float v1 = acc1[reg]; v1 = v1 > 0.f ? v1 : 0.f;
        hid[gr * 64 + ((((r)      << 1) ^ sw) >> 1)] = f2bf(v0);
        hid[gr * 64 + ((((r + 32) << 1) ^ sw) >> 1)] = f2bf(v1);
    }
    __syncthreads();

    const int gr2 = w * 32 + r;
    const int sw2 = (gr2 & 7) << 4;
    f32x16 acc2;
#pragma unroll
    for (int i = 0; i < 16; ++i) acc2[i] = bias2;
#pragma unroll
    for (int t2 = 0; t2 < 4; ++t2) {
        const int boff = (t2 * 32 + kg * 16) ^ sw2;
        bf16x8 a = *(const bf16x8*)((const char*)&hid[gr2 * 64] + boff);
        acc2 = __builtin_amdgcn_mfma_f32_32x32x16_bf16(a, b2f[t2], acc2, 0, 0, 0);
    }

#pragma unroll
    for (int reg = 0; reg < 16; ++reg) {
        const int row = (reg & 3) + 8 * (reg >> 2) + 4 * kg;
        const long eo = eb + row;
        if (r < 5 && eo < E) out[(size_t)eo * 5 + r] = acc2[reg];
    }
}

extern "C" void kernel_launch(void* const* d_in, const int* in_sizes, int n_in,
                              void* d_out, int out_size, void* d_ws, size_t ws_size,
                              hipStream_t stream)
{
    const float* x     = (const float*)d_in[0];
    const int*   ei    = (const int*)d_in[1];
    const float* eattr = (const float*)d_in[2];
    const float* W1    = (const float*)d_in[3];
    const float* b1    = (const float*)d_in[4];
    const float* W2    = (const float*)d_in[5];
    const float* b2    = (const float*)d_in[6];
    const float* Wc1   = (const float*)d_in[7];
    const float* bc1   = (const float*)d_in[8];
    const float* Wc2   = (const float*)d_in[9];
    const float* bc2   = (const float*)d_in[10];
    float* outp = (float*)d_out;

    const int N = in_sizes[0] / 32;
    const int E = in_sizes[1] / 2;

    // ---- carve workspace (~47 MB) ----
    size_t off = 0;
    char* base = (char*)d_ws;
    auto carve = [&](size_t bytes) -> void* {
        void* p = base + off;
        off += (bytes + 255) & ~(size_t)255;
        return p;
    };
    int*   degcnt = (int*)carve((size_t)2 * N * 4);
    int*   cursor = degcnt + N;
    float* dinv   = (float*)carve((size_t)N * 4);
    int*   rs     = (int*)carve((size_t)(N + 1) * 4);
    int*   bsum   = (int*)carve(512 * 4);
    int*   boff   = (int*)carve(512 * 4);
    int*   col    = (int*)carve((size_t)E * 4);
    unsigned short* hsc  = (unsigned short*)carve((size_t)N * 64 * 2);   // hsc1 then hsc2
    unsigned short* h1   = (unsigned short*)carve((size_t)N * 64 * 2);
    unsigned short* h2bf = (unsigned short*)carve((size_t)N * 64 * 2);
    short* Wc1T   = (short*)carve(9216 * 2);
    short* Wc2T   = (short*)carve(2048 * 2);
    short* W2T    = (short*)carve(4096 * 2);
    (void)ws_size; (void)n_in; (void)out_size;

    const int NB = (N + 255) / 256;
    const int EB = (E + 255) / 256;
    const int NV = (N + 3) / 4;          // nodemm32: 4 nodes/block
    const int NA = (N + 7) / 8;          // agg: 8 nodes/block
    const int NM = (N + 127) / 128;      // nodemm64 MFMA: 128 nodes/block
    const int MB = (E + 127) / 128;      // edge MLP: 128 edges/block

    hipMemsetAsync(degcnt, 0, (size_t)2 * N * 4, stream);

    k_prep<<<60, 256, 0, stream>>>(Wc1, Wc2, W2, Wc1T, Wc2T, W2T);
    k_hist<<<EB, 256, 0, stream>>>(ei, degcnt, E);
    k_dinv<<<NB, 256, 0, stream>>>(degcnt, dinv, N);
    k_bsum<<<NB, 256, 0, stream>>>(degcnt, N, bsum);
    k_boff<<<1, 512, 0, stream>>>(bsum, NB, boff);
    k_rowstart<<<NB, 256, 0, stream>>>(degcnt, boff, rs, N, E);
    k_scatter<<<EB, 256, 0, stream>>>(ei, rs, cursor, col, E);

    // layer 1
    k_nodemm32<<<NV, 256, 0, stream>>>(x, W1, dinv, hsc, N);
    k_agg_bf<1><<<NA, 256, 0, stream>>>(hsc, dinv, rs, col, b1, h1, N);
    // layer 2
    k_nodemm64_mfma<<<NM, 256, 0, stream>>>(h1, W2T, dinv, hsc, N);
    k_agg_bf<0><<<NA, 256, 0, stream>>>(hsc, dinv, rs, col, b2, h2bf, N);
    // edge MLP
    k_edge_mlp_mfma<<<MB, 256, 0, stream>>>(h2bf, eattr, ei, Wc1T, bc1, Wc2T, bc2, outp, E);
}

// Round 6
// 415.256 us; speedup vs baseline: 1.2632x; 1.1055x over previous
//
#include <hip/hip_runtime.h>
#include <hip/hip_bf16.h>

// ---------------------------------------------------------------------------
// EdgeClassifier: 2x GCNConv + edge MLP. All node intermediates bf16.
//   CSR build -> nodemm32(MFMA) -> agg -> nodemm64(MFMA) -> agg
//   -> persistent-block all-MFMA edge MLP (weights loaded once per block).
// nodemm kernels use swapped MFMA operands (A=weight rows, B=node cols) so
// each lane owns one node's row -> packed short4 stores.
// ---------------------------------------------------------------------------

typedef __attribute__((ext_vector_type(8))) short  bf16x8;
typedef __attribute__((ext_vector_type(16))) float f32x16;

__device__ inline short f2bf(float f)
{
    union { float f; unsigned u; } v; v.f = f;
    unsigned r = v.u + 0x7fff + ((v.u >> 16) & 1);   // RNE
    return (short)(r >> 16);
}

__device__ inline float2 bfp2f(unsigned u)
{
    union { unsigned u; float f; } a, b;
    a.u = u << 16;
    b.u = u & 0xffff0000u;
    return make_float2(a.f, b.f);
}

// ---------------- CSR build ----------------
__global__ __launch_bounds__(256) void k_hist(const int* __restrict__ ei, int* __restrict__ degcnt, int E)
{
    int e = blockIdx.x * 256 + threadIdx.x;
    if (e < E) atomicAdd(&degcnt[ei[E + e]], 1);
}

// dinv + per-block degree sum (fused)
__global__ __launch_bounds__(256) void k_dinv_bsum(const int* __restrict__ degcnt, float* __restrict__ dinv,
                                                   int n, int* __restrict__ bsum)
{
    __shared__ int s[256];
    int t = threadIdx.x;
    int i = blockIdx.x * 256 + t;
    int dg = (i < n) ? degcnt[i] : 0;
    if (i < n) dinv[i] = rsqrtf((float)(dg + 1));
    s[t] = dg;
    __syncthreads();
    for (int o = 128; o > 0; o >>= 1) {
        if (t < o) s[t] += s[t + o];
        __syncthreads();
    }
    if (t == 0) bsum[blockIdx.x] = s[0];
}

__global__ __launch_bounds__(512) void k_boff(const int* __restrict__ bsum, int nb, int* __restrict__ boff)
{
    __shared__ int s[512];
    int t = threadIdx.x;
    int v = (t < nb) ? bsum[t] : 0;
    s[t] = v;
    __syncthreads();
    for (int o = 1; o < 512; o <<= 1) {
        int a = (t >= o) ? s[t - o] : 0;
        __syncthreads();
        s[t] += a;
        __syncthreads();
    }
    if (t < nb) boff[t] = s[t] - v;
}

__global__ __launch_bounds__(256) void k_rowstart(const int* __restrict__ deg, const int* __restrict__ boff,
                                                  int* __restrict__ rs, int n, int total)
{
    __shared__ int s[256];
    int t = threadIdx.x;
    int i = blockIdx.x * 256 + t;
    int v = (i < n) ? deg[i] : 0;
    s[t] = v;
    __syncthreads();
    for (int o = 1; o < 256; o <<= 1) {
        int a = (t >= o) ? s[t - o] : 0;
        __syncthreads();
        s[t] += a;
        __syncthreads();
    }
    if (i < n) rs[i] = boff[blockIdx.x] + s[t] - v;
    if (i == 0) rs[n] = total;
}

__global__ __launch_bounds__(256) void k_scatter(const int* __restrict__ ei, const int* __restrict__ rs,
                                                 int* __restrict__ cursor, int* __restrict__ col, int E)
{
    int e = blockIdx.x * 256 + threadIdx.x;
    if (e < E) {
        int d = ei[E + e];
        int pos = atomicAdd(&cursor[d], 1);
        col[rs[d] + pos] = ei[e];
    }
}

// ---------------- weight prep (all bf16, transposed) ----------------
// Wc1T[64][144] | Wc2T[32][64] (class-padded) | W2T[64][64] | W1T[64][32]
__global__ __launch_bounds__(256) void k_prep(const float* __restrict__ Wc1, const float* __restrict__ Wc2,
                                              const float* __restrict__ W2, const float* __restrict__ W1,
                                              short* __restrict__ Wc1T, short* __restrict__ Wc2T,
                                              short* __restrict__ W2T, short* __restrict__ W1T)
{
    int t = blockIdx.x * 256 + threadIdx.x;
    if (t < 9216) {
        int j = t / 144, k = t - j * 144;
        Wc1T[t] = f2bf(Wc1[k * 64 + j]);
    } else if (t < 11264) {
        int u = t - 9216;
        int rr = u / 64, k = u - rr * 64;
        Wc2T[u] = (rr < 5) ? f2bf(Wc2[k * 5 + rr]) : (short)0;
    } else if (t < 15360) {
        int u = t - 11264;
        int j = u / 64, k = u - j * 64;
        W2T[u] = f2bf(W2[k * 64 + j]);
    } else if (t < 17408) {
        int u = t - 15360;
        int j = u / 32, k = u - j * 32;
        W1T[u] = f2bf(W1[k * 64 + j]);
    }
}

// ---------------- layer-1 per-node GEMM (MFMA): hsc = (x@W1)*dinv, bf16 ----------------
// Swapped operands: A = W1T rows (j), B = x cols (node). D col=node, row=j.
__global__ __launch_bounds__(256) void k_nodemm32_mfma(const float* __restrict__ x, const short* __restrict__ W1T,
                                                       const float* __restrict__ dinv,
                                                       unsigned short* __restrict__ out, int n)
{
    const int tid = threadIdx.x;
    const int w = tid >> 6, lane = tid & 63, r = lane & 31, kg = lane >> 5;
    const int nb = blockIdx.x * 128 + w * 32;

    bf16x8 a0[2], a1[2];
#pragma unroll
    for (int t = 0; t < 2; ++t) {
        a0[t] = *(const bf16x8*)&W1T[r * 32 + t * 16 + kg * 8];
        a1[t] = *(const bf16x8*)&W1T[(r + 32) * 32 + t * 16 + kg * 8];
    }

    int row = nb + r;
    if (row >= n) row = n - 1;
    f32x16 acc0 = {0.f}, acc1 = {0.f};
#pragma unroll
    for (int t = 0; t < 2; ++t) {
        const float* xr = &x[(size_t)row * 32 + t * 16 + kg * 8];
        float4 lo = *(const float4*)xr;
        float4 hi = *(const float4*)(xr + 4);
        bf16x8 b;
        b[0] = f2bf(lo.x); b[1] = f2bf(lo.y); b[2] = f2bf(lo.z); b[3] = f2bf(lo.w);
        b[4] = f2bf(hi.x); b[5] = f2bf(hi.y); b[6] = f2bf(hi.z); b[7] = f2bf(hi.w);
        acc0 = __builtin_amdgcn_mfma_f32_32x32x16_bf16(a0[t], b, acc0, 0, 0, 0);
        acc1 = __builtin_amdgcn_mfma_f32_32x32x16_bf16(a1[t], b, acc1, 0, 0, 0);
    }

    const int node = nb + r;
    if (node < n) {
        const float dv = dinv[node];
#pragma unroll
        for (int q = 0; q < 4; ++q) {
            const int j0 = 8 * q + 4 * kg;
            short4 s0, s1;
            s0.x = f2bf(acc0[4 * q]     * dv); s0.y = f2bf(acc0[4 * q + 1] * dv);
            s0.z = f2bf(acc0[4 * q + 2] * dv); s0.w = f2bf(acc0[4 * q + 3] * dv);
            s1.x = f2bf(acc1[4 * q]     * dv); s1.y = f2bf(acc1[4 * q + 1] * dv);
            s1.z = f2bf(acc1[4 * q + 2] * dv); s1.w = f2bf(acc1[4 * q + 3] * dv);
            *(short4*)&out[(size_t)node * 64 + j0]      = s0;
            *(short4*)&out[(size_t)node * 64 + j0 + 32] = s1;
        }
    }
}

// ---------------- layer-2 per-node GEMM (MFMA): hsc2 = (h1@W2)*dinv, bf16 ----------------
__global__ __launch_bounds__(256) void k_nodemm64_mfma(const unsigned short* __restrict__ h1,
                                                       const short* __restrict__ W2T,
                                                       const float* __restrict__ dinv,
                                                       unsigned short* __restrict__ out, int n)
{
    const int tid = threadIdx.x;
    const int w = tid >> 6, lane = tid & 63, r = lane & 31, kg = lane >> 5;
    const int nb = blockIdx.x * 128 + w * 32;

    bf16x8 a0[4], a1[4];
#pragma unroll
    for (int t = 0; t < 4; ++t) {
        a0[t] = *(const bf16x8*)&W2T[r * 64 + t * 16 + kg * 8];
        a1[t] = *(const bf16x8*)&W2T[(r + 32) * 64 + t * 16 + kg * 8];
    }

    int row = nb + r;
    if (row >= n) row = n - 1;
    f32x16 acc0 = {0.f}, acc1 = {0.f};
#pragma unroll
    for (int t = 0; t < 4; ++t) {
        bf16x8 b = *(const bf16x8*)&h1[(size_t)row * 64 + t * 16 + kg * 8];
        acc0 = __builtin_amdgcn_mfma_f32_32x32x16_bf16(a0[t], b, acc0, 0, 0, 0);
        acc1 = __builtin_amdgcn_mfma_f32_32x32x16_bf16(a1[t], b, acc1, 0, 0, 0);
    }

    const int node = nb + r;
    if (node < n) {
        const float dv = dinv[node];
#pragma unroll
        for (int q = 0; q < 4; ++q) {
            const int j0 = 8 * q + 4 * kg;
            short4 s0, s1;
            s0.x = f2bf(acc0[4 * q]     * dv); s0.y = f2bf(acc0[4 * q + 1] * dv);
            s0.z = f2bf(acc0[4 * q + 2] * dv); s0.w = f2bf(acc0[4 * q + 3] * dv);
            s1.x = f2bf(acc1[4 * q]     * dv); s1.y = f2bf(acc1[4 * q + 1] * dv);
            s1.z = f2bf(acc1[4 * q + 2] * dv); s1.w = f2bf(acc1[4 * q + 3] * dv);
            *(short4*)&out[(size_t)node * 64 + j0]      = s0;
            *(short4*)&out[(size_t)node * 64 + j0 + 32] = s1;
        }
    }
}

// ---------------- aggregation (bf16): out[v][:] = f(dinv[v]*(self+sum_nb) + b) ----------------
// 2 nodes per wave, 32 lanes per node, bf16x2 per lane; unroll 8 (16 loads in flight/wave).
template <int RELU>
__global__ __launch_bounds__(256) void k_agg_bf(const unsigned short* __restrict__ hsc,
                                                const float* __restrict__ dinv,
                                                const int* __restrict__ rs, const int* __restrict__ col,
                                                const float* __restrict__ bias,
                                                unsigned short* __restrict__ out, int n)
{
    const int tid = threadIdx.x;
    const int l   = tid & 31;
    const int v   = blockIdx.x * 8 + (tid >> 5);
    if (v >= n) return;

    float2 acc = bfp2f(*(const unsigned*)(hsc + (size_t)v * 64 + l * 2));   // self
    int i = rs[v];
    const int end = rs[v + 1];
    for (; i + 8 <= end; i += 8) {
        int c0 = col[i],     c1 = col[i + 1], c2 = col[i + 2], c3 = col[i + 3];
        int c4 = col[i + 4], c5 = col[i + 5], c6 = col[i + 6], c7 = col[i + 7];
        unsigned u0 = *(const unsigned*)(hsc + (size_t)c0 * 64 + l * 2);
        unsigned u1 = *(const unsigned*)(hsc + (size_t)c1 * 64 + l * 2);
        unsigned u2 = *(const unsigned*)(hsc + (size_t)c2 * 64 + l * 2);
        unsigned u3 = *(const unsigned*)(hsc + (size_t)c3 * 64 + l * 2);
        unsigned u4 = *(const unsigned*)(hsc + (size_t)c4 * 64 + l * 2);
        unsigned u5 = *(const unsigned*)(hsc + (size_t)c5 * 64 + l * 2);
        unsigned u6 = *(const unsigned*)(hsc + (size_t)c6 * 64 + l * 2);
        unsigned u7 = *(const unsigned*)(hsc + (size_t)c7 * 64 + l * 2);
        float2 a0 = bfp2f(u0), a1 = bfp2f(u1), a2 = bfp2f(u2), a3 = bfp2f(u3);
        float2 a4 = bfp2f(u4), a5 = bfp2f(u5), a6 = bfp2f(u6), a7 = bfp2f(u7);
        acc.x += (a0.x + a1.x) + (a2.x + a3.x) + (a4.x + a5.x) + (a6.x + a7.x);
        acc.y += (a0.y + a1.y) + (a2.y + a3.y) + (a4.y + a5.y) + (a6.y + a7.y);
    }
    for (; i + 4 <= end; i += 4) {
        int c0 = col[i], c1 = col[i + 1], c2 = col[i + 2], c3 = col[i + 3];
        unsigned u0 = *(const unsigned*)(hsc + (size_t)c0 * 64 + l * 2);
        unsigned u1 = *(const unsigned*)(hsc + (size_t)c1 * 64 + l * 2);
        unsigned u2 = *(const unsigned*)(hsc + (size_t)c2 * 64 + l * 2);
        unsigned u3 = *(const unsigned*)(hsc + (size_t)c3 * 64 + l * 2);
        float2 a0 = bfp2f(u0), a1 = bfp2f(u1), a2 = bfp2f(u2), a3 = bfp2f(u3);
        acc.x += (a0.x + a1.x) + (a2.x + a3.x);
        acc.y += (a0.y + a1.y) + (a2.y + a3.y);
    }
    for (; i < end; ++i) {
        float2 a = bfp2f(*(const unsigned*)(hsc + (size_t)col[i] * 64 + l * 2));
        acc.x += a.x; acc.y += a.y;
    }
    const float dv = dinv[v];
    float r0 = fmaf(dv, acc.x, bias[l * 2]);
    float r1 = fmaf(dv, acc.y, bias[l * 2 + 1]);
    if (RELU) { r0 = r0 > 0.f ? r0 : 0.f; r1 = r1 > 0.f ? r1 : 0.f; }
    unsigned o = (unsigned)(unsigned short)f2bf(r0) | ((unsigned)(unsigned short)f2bf(r1) << 16);
    *(unsigned*)(out + (size_t)v * 64 + l * 2) = o;
}

// ---------------- persistent-block MFMA edge MLP ----------------
// Weights loaded once per block; grid-stride over 128-edge tiles; next tile's
// ei indices prefetched before the MFMA section. Each wave uses only its own
// 32-row LDS slab -> NO barriers needed.
__global__ __launch_bounds__(256) void k_edge_mlp_mfma(
    const unsigned short* __restrict__ h2bf, const float* __restrict__ eattr,
    const int* __restrict__ ei,
    const short* __restrict__ Wc1T, const float* __restrict__ bc1,
    const short* __restrict__ Wc2T, const float* __restrict__ bc2,
    float* __restrict__ out, int E, int ntiles)
{
    __shared__ short hid[128 * 64];   // 16 KB, XOR-swizzled, per-wave slabs

    const int tid = threadIdx.x;
    const int w = tid >> 6, lane = tid & 63, r = lane & 31, kg = lane >> 5;

    bf16x8 b1f[9][2];
#pragma unroll
    for (int t = 0; t < 9; ++t) {
#pragma unroll
        for (int nt = 0; nt < 2; ++nt)
            b1f[t][nt] = *(const bf16x8*)&Wc1T[(r + nt * 32) * 144 + t * 16 + kg * 8];
    }
    bf16x8 b2f[4];
#pragma unroll
    for (int t2 = 0; t2 < 4; ++t2)
        b2f[t2] = *(const bf16x8*)&Wc2T[r * 64 + t2 * 16 + kg * 8];

    const float bias0 = bc1[r];
    const float bias1 = bc1[r + 32];
    const float bias2 = (r < 5) ? bc2[r] : 0.f;

    int tile = blockIdx.x;
    if (tile >= ntiles) return;
    long e = (long)tile * 128 + w * 32 + r;
    if (e >= E) e = E - 1;
    int s = ei[e];
    int d = ei[E + e];

    while (true) {
        const long eb = (long)tile * 128 + w * 32;
        const unsigned short* srow = &h2bf[(size_t)s * 64];
        const unsigned short* drow = &h2bf[(size_t)d * 64];
        const float* arow = &eattr[(size_t)e * 16];

        bf16x8 av[8];
#pragma unroll
        for (int t = 0; t < 4; ++t) av[t] = *(const bf16x8*)&srow[t * 16 + kg * 8];
#pragma unroll
        for (int t = 0; t < 4; ++t) av[4 + t] = *(const bf16x8*)&drow[t * 16 + kg * 8];
        float4 alo = *(const float4*)&arow[kg * 8];
        float4 ahi = *(const float4*)&arow[kg * 8 + 4];

        // prefetch next tile's indices (hides ei->gather chain under this tile)
        const int ntile = tile + gridDim.x;
        const bool more = (ntile < ntiles);
        int sn = 0, dn = 0;
        long en = 0;
        if (more) {
            en = (long)ntile * 128 + w * 32 + r;
            if (en >= E) en = E - 1;
            sn = ei[en];
            dn = ei[E + en];
        }

        f32x16 acc0, acc1;
#pragma unroll
        for (int i = 0; i < 16; ++i) { acc0[i] = bias0; acc1[i] = bias1; }

#pragma unroll
        for (int t = 0; t < 8; ++t) {
            acc0 = __builtin_amdgcn_mfma_f32_32x32x16_bf16(av[t], b1f[t][0], acc0, 0, 0, 0);
            acc1 = __builtin_amdgcn_mfma_f32_32x32x16_bf16(av[t], b1f[t][1], acc1, 0, 0, 0);
        }
        {
            bf16x8 aa;
            aa[0] = f2bf(alo.x); aa[1] = f2bf(alo.y); aa[2] = f2bf(alo.z); aa[3] = f2bf(alo.w);
            aa[4] = f2bf(ahi.x); aa[5] = f2bf(ahi.y); aa[6] = f2bf(ahi.z); aa[7] = f2bf(ahi.w);
            acc0 = __builtin_amdgcn_mfma_f32_32x32x16_bf16(aa, b1f[8][0], acc0, 0, 0, 0);
            acc1 = __builtin_amdgcn_mfma_f32_32x32x16_bf16(aa, b1f[8][1], acc1, 0, 0, 0);
        }

        // epilogue 1: relu -> bf16 -> swizzled LDS (own slab, no barrier)
#pragma unroll
        for (int reg = 0; reg < 16; ++reg) {
            const int row = (reg & 3) + 8 * (reg >> 2) + 4 * kg;
            const int gr  = w * 32 + row;
            const int sw  = (gr & 7) << 4;
            float v0 = acc0[reg]; v0 = v0 > 0.f ? v0 : 0.f;
            float v1 = acc1[reg]; v1 = v1 > 0.f ? v1 : 0.f;
            hid[gr * 64 + ((((r)      << 1) ^ sw) >> 1)] = f2bf(v0);
            hid[gr * 64 + ((((r + 32) << 1) ^ sw) >> 1)] = f2bf(v1);
        }

        // layer 2
        const int gr2 = w * 32 + r;
        const int sw2 = (gr2 & 7) << 4;
        f32x16 acc2;
#pragma unroll
        for (int i = 0; i < 16; ++i) acc2[i] = bias2;
#pragma unroll
        for (int t2 = 0; t2 < 4; ++t2) {
            const int boff = (t2 * 32 + kg * 16) ^ sw2;
            bf16x8 a = *(const bf16x8*)((const char*)&hid[gr2 * 64] + boff);
            acc2 = __builtin_amdgcn_mfma_f32_32x32x16_bf16(a, b2f[t2], acc2, 0, 0, 0);
        }

#pragma unroll
        for (int reg = 0; reg < 16; ++reg) {
            const int row = (reg & 3) + 8 * (reg >> 2) + 4 * kg;
            const long eo = eb + row;
            if (r < 5 && eo < E) out[(size_t)eo * 5 + r] = acc2[reg];
        }

        if (!more) break;
        tile = ntile; e = en; s = sn; d = dn;
    }
}

extern "C" void kernel_launch(void* const* d_in, const int* in_sizes, int n_in,
                              void* d_out, int out_size, void* d_ws, size_t ws_size,
                              hipStream_t stream)
{
    const float* x     = (const float*)d_in[0];
    const int*   ei    = (const int*)d_in[1];
    const float* eattr = (const float*)d_in[2];
    const float* W1    = (const float*)d_in[3];
    const float* b1    = (const float*)d_in[4];
    const float* W2    = (const float*)d_in[5];
    const float* b2    = (const float*)d_in[6];
    const float* Wc1   = (const float*)d_in[7];
    const float* bc1   = (const float*)d_in[8];
    const float* Wc2   = (const float*)d_in[9];
    const float* bc2   = (const float*)d_in[10];
    float* outp = (float*)d_out;

    const int N = in_sizes[0] / 32;
    const int E = in_sizes[1] / 2;

    // ---- carve workspace (~46 MB) ----
    size_t off = 0;
    char* base = (char*)d_ws;
    auto carve = [&](size_t bytes) -> void* {
        void* p = base + off;
        off += (bytes + 255) & ~(size_t)255;
        return p;
    };
    int*   degcnt = (int*)carve((size_t)2 * N * 4);
    int*   cursor = degcnt + N;
    float* dinv   = (float*)carve((size_t)N * 4);
    int*   rs     = (int*)carve((size_t)(N + 1) * 4);
    int*   bsum   = (int*)carve(512 * 4);
    int*   boff   = (int*)carve(512 * 4);
    int*   col    = (int*)carve((size_t)E * 4);
    unsigned short* hsc  = (unsigned short*)carve((size_t)N * 64 * 2);
    unsigned short* h1   = (unsigned short*)carve((size_t)N * 64 * 2);
    unsigned short* h2bf = (unsigned short*)carve((size_t)N * 64 * 2);
    short* Wc1T   = (short*)carve(9216 * 2);
    short* Wc2T   = (short*)carve(2048 * 2);
    short* W2T    = (short*)carve(4096 * 2);
    short* W1T    = (short*)carve(2048 * 2);
    (void)ws_size; (void)n_in; (void)out_size;

    const int NB = (N + 255) / 256;
    const int EB = (E + 255) / 256;
    const int NA = (N + 7) / 8;          // agg: 8 nodes/block
    const int NM = (N + 127) / 128;      // nodemm MFMA: 128 nodes/block
    const int NT = (E + 127) / 128;      // edge-MLP tiles
    const int MG = NT < 2048 ? NT : 2048;

    hipMemsetAsync(degcnt, 0, (size_t)2 * N * 4, stream);

    k_prep<<<68, 256, 0, stream>>>(Wc1, Wc2, W2, W1, Wc1T, Wc2T, W2T, W1T);
    k_hist<<<EB, 256, 0, stream>>>(ei, degcnt, E);
    k_dinv_bsum<<<NB, 256, 0, stream>>>(degcnt, dinv, N, bsum);
    k_boff<<<1, 512, 0, stream>>>(bsum, NB, boff);
    k_rowstart<<<NB, 256, 0, stream>>>(degcnt, boff, rs, N, E);
    k_scatter<<<EB, 256, 0, stream>>>(ei, rs, cursor, col, E);

    // layer 1
    k_nodemm32_mfma<<<NM, 256, 0, stream>>>(x, W1T, dinv, hsc, N);
    k_agg_bf<1><<<NA, 256, 0, stream>>>(hsc, dinv, rs, col, b1, h1, N);
    // layer 2
    k_nodemm64_mfma<<<NM, 256, 0, stream>>>(h1, W2T, dinv, hsc, N);
    k_agg_bf<0><<<NA, 256, 0, stream>>>(hsc, dinv, rs, col, b2, h2bf, N);
    // edge MLP (persistent blocks)
    k_edge_mlp_mfma<<<MG, 256, 0, stream>>>(h2bf, eattr, ei, Wc1T, bc1, Wc2T, bc2, outp, E, NT);
}

// Round 7
// 404.733 us; speedup vs baseline: 1.2960x; 1.0260x over previous
//
#include <hip/hip_runtime.h>
#include <hip/hip_bf16.h>

// ---------------------------------------------------------------------------
// EdgeClassifier: 2x GCNConv + edge MLP. All node intermediates bf16.
//   CSR build -> nodemm32(MFMA) -> agg -> nodemm64(MFMA) -> agg
//   -> persistent-block all-MFMA edge MLP, edges processed in CSR(dst) order
//     so dst-row gathers merge/broadcast (~2 distinct dst per 32-edge wave).
// Scatter records (src=col, dst=dstarr, edge-id=eid) per CSR slot; MLP
// scatters outputs via eid (wave __shfl to map C/D rows -> edge ids).
// ---------------------------------------------------------------------------

typedef __attribute__((ext_vector_type(8))) short  bf16x8;
typedef __attribute__((ext_vector_type(16))) float f32x16;

__device__ inline short f2bf(float f)
{
    union { float f; unsigned u; } v; v.f = f;
    unsigned r = v.u + 0x7fff + ((v.u >> 16) & 1);   // RNE
    return (short)(r >> 16);
}

__device__ inline float2 bfp2f(unsigned u)
{
    union { unsigned u; float f; } a, b;
    a.u = u << 16;
    b.u = u & 0xffff0000u;
    return make_float2(a.f, b.f);
}

// ---------------- CSR build ----------------
__global__ __launch_bounds__(256) void k_hist(const int* __restrict__ ei, int* __restrict__ degcnt, int E)
{
    int e = blockIdx.x * 256 + threadIdx.x;
    if (e < E) atomicAdd(&degcnt[ei[E + e]], 1);
}

__global__ __launch_bounds__(256) void k_dinv_bsum(const int* __restrict__ degcnt, float* __restrict__ dinv,
                                                   int n, int* __restrict__ bsum)
{
    __shared__ int s[256];
    int t = threadIdx.x;
    int i = blockIdx.x * 256 + t;
    int dg = (i < n) ? degcnt[i] : 0;
    if (i < n) dinv[i] = rsqrtf((float)(dg + 1));
    s[t] = dg;
    __syncthreads();
    for (int o = 128; o > 0; o >>= 1) {
        if (t < o) s[t] += s[t + o];
        __syncthreads();
    }
    if (t == 0) bsum[blockIdx.x] = s[0];
}

__global__ __launch_bounds__(512) void k_boff(const int* __restrict__ bsum, int nb, int* __restrict__ boff)
{
    __shared__ int s[512];
    int t = threadIdx.x;
    int v = (t < nb) ? bsum[t] : 0;
    s[t] = v;
    __syncthreads();
    for (int o = 1; o < 512; o <<= 1) {
        int a = (t >= o) ? s[t - o] : 0;
        __syncthreads();
        s[t] += a;
        __syncthreads();
    }
    if (t < nb) boff[t] = s[t] - v;
}

__global__ __launch_bounds__(256) void k_rowstart(const int* __restrict__ deg, const int* __restrict__ boff,
                                                  int* __restrict__ rs, int n, int total)
{
    __shared__ int s[256];
    int t = threadIdx.x;
    int i = blockIdx.x * 256 + t;
    int v = (i < n) ? deg[i] : 0;
    s[t] = v;
    __syncthreads();
    for (int o = 1; o < 256; o <<= 1) {
        int a = (t >= o) ? s[t - o] : 0;
        __syncthreads();
        s[t] += a;
        __syncthreads();
    }
    if (i < n) rs[i] = boff[blockIdx.x] + s[t] - v;
    if (i == 0) rs[n] = total;
}

// CSR scatter: per slot record src (col), dst (dstarr) and original edge id (eid)
__global__ __launch_bounds__(256) void k_scatter(const int* __restrict__ ei, const int* __restrict__ rs,
                                                 int* __restrict__ cursor, int* __restrict__ col,
                                                 int* __restrict__ dstarr, int* __restrict__ eid, int E)
{
    int e = blockIdx.x * 256 + threadIdx.x;
    if (e < E) {
        int d = ei[E + e];
        int pos = atomicAdd(&cursor[d], 1);
        int idx = rs[d] + pos;
        col[idx]    = ei[e];
        dstarr[idx] = d;
        eid[idx]    = e;
    }
}

// ---------------- weight prep (all bf16, transposed) ----------------
// Wc1T[64][144] | Wc2T[32][64] (class-padded) | W2T[64][64] | W1T[64][32]
__global__ __launch_bounds__(256) void k_prep(const float* __restrict__ Wc1, const float* __restrict__ Wc2,
                                              const float* __restrict__ W2, const float* __restrict__ W1,
                                              short* __restrict__ Wc1T, short* __restrict__ Wc2T,
                                              short* __restrict__ W2T, short* __restrict__ W1T)
{
    int t = blockIdx.x * 256 + threadIdx.x;
    if (t < 9216) {
        int j = t / 144, k = t - j * 144;
        Wc1T[t] = f2bf(Wc1[k * 64 + j]);
    } else if (t < 11264) {
        int u = t - 9216;
        int rr = u / 64, k = u - rr * 64;
        Wc2T[u] = (rr < 5) ? f2bf(Wc2[k * 5 + rr]) : (short)0;
    } else if (t < 15360) {
        int u = t - 11264;
        int j = u / 64, k = u - j * 64;
        W2T[u] = f2bf(W2[k * 64 + j]);
    } else if (t < 17408) {
        int u = t - 15360;
        int j = u / 32, k = u - j * 32;
        W1T[u] = f2bf(W1[k * 64 + j]);
    }
}

// ---------------- layer-1 per-node GEMM (MFMA): hsc = (x@W1)*dinv, bf16 ----------------
__global__ __launch_bounds__(256) void k_nodemm32_mfma(const float* __restrict__ x, const short* __restrict__ W1T,
                                                       const float* __restrict__ dinv,
                                                       unsigned short* __restrict__ out, int n)
{
    const int tid = threadIdx.x;
    const int w = tid >> 6, lane = tid & 63, r = lane & 31, kg = lane >> 5;
    const int nb = blockIdx.x * 128 + w * 32;

    bf16x8 a0[2], a1[2];
#pragma unroll
    for (int t = 0; t < 2; ++t) {
        a0[t] = *(const bf16x8*)&W1T[r * 32 + t * 16 + kg * 8];
        a1[t] = *(const bf16x8*)&W1T[(r + 32) * 32 + t * 16 + kg * 8];
    }

    int row = nb + r;
    if (row >= n) row = n - 1;
    f32x16 acc0 = {0.f}, acc1 = {0.f};
#pragma unroll
    for (int t = 0; t < 2; ++t) {
        const float* xr = &x[(size_t)row * 32 + t * 16 + kg * 8];
        float4 lo = *(const float4*)xr;
        float4 hi = *(const float4*)(xr + 4);
        bf16x8 b;
        b[0] = f2bf(lo.x); b[1] = f2bf(lo.y); b[2] = f2bf(lo.z); b[3] = f2bf(lo.w);
        b[4] = f2bf(hi.x); b[5] = f2bf(hi.y); b[6] = f2bf(hi.z); b[7] = f2bf(hi.w);
        acc0 = __builtin_amdgcn_mfma_f32_32x32x16_bf16(a0[t], b, acc0, 0, 0, 0);
        acc1 = __builtin_amdgcn_mfma_f32_32x32x16_bf16(a1[t], b, acc1, 0, 0, 0);
    }

    const int node = nb + r;
    if (node < n) {
        const float dv = dinv[node];
#pragma unroll
        for (int q = 0; q < 4; ++q) {
            const int j0 = 8 * q + 4 * kg;
            short4 s0, s1;
            s0.x = f2bf(acc0[4 * q]     * dv); s0.y = f2bf(acc0[4 * q + 1] * dv);
            s0.z = f2bf(acc0[4 * q + 2] * dv); s0.w = f2bf(acc0[4 * q + 3] * dv);
            s1.x = f2bf(acc1[4 * q]     * dv); s1.y = f2bf(acc1[4 * q + 1] * dv);
            s1.z = f2bf(acc1[4 * q + 2] * dv); s1.w = f2bf(acc1[4 * q + 3] * dv);
            *(short4*)&out[(size_t)node * 64 + j0]      = s0;
            *(short4*)&out[(size_t)node * 64 + j0 + 32] = s1;
        }
    }
}

// ---------------- layer-2 per-node GEMM (MFMA): hsc2 = (h1@W2)*dinv, bf16 ----------------
__global__ __launch_bounds__(256) void k_nodemm64_mfma(const unsigned short* __restrict__ h1,
                                                       const short* __restrict__ W2T,
                                                       const float* __restrict__ dinv,
                                                       unsigned short* __restrict__ out, int n)
{
    const int tid = threadIdx.x;
    const int w = tid >> 6, lane = tid & 63, r = lane & 31, kg = lane >> 5;
    const int nb = blockIdx.x * 128 + w * 32;

    bf16x8 a0[4], a1[4];
#pragma unroll
    for (int t = 0; t < 4; ++t) {
        a0[t] = *(const bf16x8*)&W2T[r * 64 + t * 16 + kg * 8];
        a1[t] = *(const bf16x8*)&W2T[(r + 32) * 64 + t * 16 + kg * 8];
    }

    int row = nb + r;
    if (row >= n) row = n - 1;
    f32x16 acc0 = {0.f}, acc1 = {0.f};
#pragma unroll
    for (int t = 0; t < 4; ++t) {
        bf16x8 b = *(const bf16x8*)&h1[(size_t)row * 64 + t * 16 + kg * 8];
        acc0 = __builtin_amdgcn_mfma_f32_32x32x16_bf16(a0[t], b, acc0, 0, 0, 0);
        acc1 = __builtin_amdgcn_mfma_f32_32x32x16_bf16(a1[t], b, acc1, 0, 0, 0);
    }

    const int node = nb + r;
    if (node < n) {
        const float dv = dinv[node];
#pragma unroll
        for (int q = 0; q < 4; ++q) {
            const int j0 = 8 * q + 4 * kg;
            short4 s0, s1;
            s0.x = f2bf(acc0[4 * q]     * dv); s0.y = f2bf(acc0[4 * q + 1] * dv);
            s0.z = f2bf(acc0[4 * q + 2] * dv); s0.w = f2bf(acc0[4 * q + 3] * dv);
            s1.x = f2bf(acc1[4 * q]     * dv); s1.y = f2bf(acc1[4 * q + 1] * dv);
            s1.z = f2bf(acc1[4 * q + 2] * dv); s1.w = f2bf(acc1[4 * q + 3] * dv);
            *(short4*)&out[(size_t)node * 64 + j0]      = s0;
            *(short4*)&out[(size_t)node * 64 + j0 + 32] = s1;
        }
    }
}

// ---------------- aggregation (bf16) ----------------
template <int RELU>
__global__ __launch_bounds__(256) void k_agg_bf(const unsigned short* __restrict__ hsc,
                                                const float* __restrict__ dinv,
                                                const int* __restrict__ rs, const int* __restrict__ col,
                                                const float* __restrict__ bias,
                                                unsigned short* __restrict__ out, int n)
{
    const int tid = threadIdx.x;
    const int l   = tid & 31;
    const int v   = blockIdx.x * 8 + (tid >> 5);
    if (v >= n) return;

    float2 acc = bfp2f(*(const unsigned*)(hsc + (size_t)v * 64 + l * 2));   // self
    int i = rs[v];
    const int end = rs[v + 1];
    for (; i + 8 <= end; i += 8) {
        int c0 = col[i],     c1 = col[i + 1], c2 = col[i + 2], c3 = col[i + 3];
        int c4 = col[i + 4], c5 = col[i + 5], c6 = col[i + 6], c7 = col[i + 7];
        unsigned u0 = *(const unsigned*)(hsc + (size_t)c0 * 64 + l * 2);
        unsigned u1 = *(const unsigned*)(hsc + (size_t)c1 * 64 + l * 2);
        unsigned u2 = *(const unsigned*)(hsc + (size_t)c2 * 64 + l * 2);
        unsigned u3 = *(const unsigned*)(hsc + (size_t)c3 * 64 + l * 2);
        unsigned u4 = *(const unsigned*)(hsc + (size_t)c4 * 64 + l * 2);
        unsigned u5 = *(const unsigned*)(hsc + (size_t)c5 * 64 + l * 2);
        unsigned u6 = *(const unsigned*)(hsc + (size_t)c6 * 64 + l * 2);
        unsigned u7 = *(const unsigned*)(hsc + (size_t)c7 * 64 + l * 2);
        float2 a0 = bfp2f(u0), a1 = bfp2f(u1), a2 = bfp2f(u2), a3 = bfp2f(u3);
        float2 a4 = bfp2f(u4), a5 = bfp2f(u5), a6 = bfp2f(u6), a7 = bfp2f(u7);
        acc.x += (a0.x + a1.x) + (a2.x + a3.x) + (a4.x + a5.x) + (a6.x + a7.x);
        acc.y += (a0.y + a1.y) + (a2.y + a3.y) + (a4.y + a5.y) + (a6.y + a7.y);
    }
    for (; i + 4 <= end; i += 4) {
        int c0 = col[i], c1 = col[i + 1], c2 = col[i + 2], c3 = col[i + 3];
        unsigned u0 = *(const unsigned*)(hsc + (size_t)c0 * 64 + l * 2);
        unsigned u1 = *(const unsigned*)(hsc + (size_t)c1 * 64 + l * 2);
        unsigned u2 = *(const unsigned*)(hsc + (size_t)c2 * 64 + l * 2);
        unsigned u3 = *(const unsigned*)(hsc + (size_t)c3 * 64 + l * 2);
        float2 a0 = bfp2f(u0), a1 = bfp2f(u1), a2 = bfp2f(u2), a3 = bfp2f(u3);
        acc.x += (a0.x + a1.x) + (a2.x + a3.x);
        acc.y += (a0.y + a1.y) + (a2.y + a3.y);
    }
    for (; i < end; ++i) {
        float2 a = bfp2f(*(const unsigned*)(hsc + (size_t)col[i] * 64 + l * 2));
        acc.x += a.x; acc.y += a.y;
    }
    const float dv = dinv[v];
    float r0 = fmaf(dv, acc.x, bias[l * 2]);
    float r1 = fmaf(dv, acc.y, bias[l * 2 + 1]);
    if (RELU) { r0 = r0 > 0.f ? r0 : 0.f; r1 = r1 > 0.f ? r1 : 0.f; }
    unsigned o = (unsigned)(unsigned short)f2bf(r0) | ((unsigned)(unsigned short)f2bf(r1) << 16);
    *(unsigned*)(out + (size_t)v * 64 + l * 2) = o;
}

// ---------------- persistent-block MFMA edge MLP, CSR(dst)-ordered ----------------
// Wave = 32 consecutive CSR slots: dst rows nearly uniform (broadcast-merge),
// src rows random, attr gathered by original edge id, output scattered by eid.
__global__ __launch_bounds__(256) void k_edge_mlp_mfma(
    const unsigned short* __restrict__ h2bf, const float* __restrict__ eattr,
    const int* __restrict__ colv, const int* __restrict__ dstv, const int* __restrict__ eidv,
    const short* __restrict__ Wc1T, const float* __restrict__ bc1,
    const short* __restrict__ Wc2T, const float* __restrict__ bc2,
    float* __restrict__ out, int E, int ntiles)
{
    __shared__ short hid[128 * 64];   // 16 KB, XOR-swizzled, per-wave slabs

    const int tid = threadIdx.x;
    const int w = tid >> 6, lane = tid & 63, r = lane & 31, kg = lane >> 5;

    bf16x8 b1f[9][2];
#pragma unroll
    for (int t = 0; t < 9; ++t) {
#pragma unroll
        for (int nt = 0; nt < 2; ++nt)
            b1f[t][nt] = *(const bf16x8*)&Wc1T[(r + nt * 32) * 144 + t * 16 + kg * 8];
    }
    bf16x8 b2f[4];
#pragma unroll
    for (int t2 = 0; t2 < 4; ++t2)
        b2f[t2] = *(const bf16x8*)&Wc2T[r * 64 + t2 * 16 + kg * 8];

    const float bias0 = bc1[r];
    const float bias1 = bc1[r + 32];
    const float bias2 = (r < 5) ? bc2[r] : 0.f;

    int tile = blockIdx.x;
    if (tile >= ntiles) return;
    {
        long i0 = (long)tile * 128 + w * 32 + r;
        if (i0 >= E) i0 = E - 1;
        int s = colv[i0];
        int d = dstv[i0];
        int e = eidv[i0];

        while (true) {
            const long eb = (long)tile * 128 + w * 32;   // CSR slot base of this wave
            const unsigned short* srow = &h2bf[(size_t)s * 64];
            const unsigned short* drow = &h2bf[(size_t)d * 64];
            const float* arow = &eattr[(size_t)e * 16];

            bf16x8 av[8];
#pragma unroll
            for (int t = 0; t < 4; ++t) av[t] = *(const bf16x8*)&srow[t * 16 + kg * 8];
#pragma unroll
            for (int t = 0; t < 4; ++t) av[4 + t] = *(const bf16x8*)&drow[t * 16 + kg * 8];
            float4 alo = *(const float4*)&arow[kg * 8];
            float4 ahi = *(const float4*)&arow[kg * 8 + 4];

            // prefetch next tile's CSR triple
            const int ntile = tile + gridDim.x;
            const bool more = (ntile < ntiles);
            int sn = 0, dn = 0, en = 0;
            if (more) {
                long i1 = (long)ntile * 128 + w * 32 + r;
                if (i1 >= E) i1 = E - 1;
                sn = colv[i1];
                dn = dstv[i1];
                en = eidv[i1];
            }

            f32x16 acc0, acc1;
#pragma unroll
            for (int i = 0; i < 16; ++i) { acc0[i] = bias0; acc1[i] = bias1; }

#pragma unroll
            for (int t = 0; t < 8; ++t) {
                acc0 = __builtin_amdgcn_mfma_f32_32x32x16_bf16(av[t], b1f[t][0], acc0, 0, 0, 0);
                acc1 = __builtin_amdgcn_mfma_f32_32x32x16_bf16(av[t], b1f[t][1], acc1, 0, 0, 0);
            }
            {
                bf16x8 aa;
                aa[0] = f2bf(alo.x); aa[1] = f2bf(alo.y); aa[2] = f2bf(alo.z); aa[3] = f2bf(alo.w);
                aa[4] = f2bf(ahi.x); aa[5] = f2bf(ahi.y); aa[6] = f2bf(ahi.z); aa[7] = f2bf(ahi.w);
                acc0 = __builtin_amdgcn_mfma_f32_32x32x16_bf16(aa, b1f[8][0], acc0, 0, 0, 0);
                acc1 = __builtin_amdgcn_mfma_f32_32x32x16_bf16(aa, b1f[8][1], acc1, 0, 0, 0);
            }

            // epilogue 1: relu -> bf16 -> swizzled LDS (own slab, no barrier)
#pragma unroll
            for (int reg = 0; reg < 16; ++reg) {
                const int row = (reg & 3) + 8 * (reg >> 2) + 4 * kg;
                const int gr  = w * 32 + row;
                const int sw  = (gr & 7) << 4;
                float v0 = acc0[reg]; v0 = v0 > 0.f ? v0 : 0.f;
                float v1 = acc1[reg]; v1 = v1 > 0.f ? v1 : 0.f;
                hid[gr * 64 + ((((r)      << 1) ^ sw) >> 1)] = f2bf(v0);
                hid[gr * 64 + ((((r + 32) << 1) ^ sw) >> 1)] = f2bf(v1);
            }

            // layer 2
            const int gr2 = w * 32 + r;
            const int sw2 = (gr2 & 7) << 4;
            f32x16 acc2;
#pragma unroll
            for (int i = 0; i < 16; ++i) acc2[i] = bias2;
#pragma unroll
            for (int t2 = 0; t2 < 4; ++t2) {
                const int boff = (t2 * 32 + kg * 16) ^ sw2;
                bf16x8 a = *(const bf16x8*)((const char*)&hid[gr2 * 64] + boff);
                acc2 = __builtin_amdgcn_mfma_f32_32x32x16_bf16(a, b2f[t2], acc2, 0, 0, 0);
            }

            // epilogue 2: scatter rows to original edge ids (eid via wave shuffle)
#pragma unroll
            for (int reg = 0; reg < 16; ++reg) {
                const int row = (reg & 3) + 8 * (reg >> 2) + 4 * kg;
                const int erow = __shfl(e, row);      // lane 'row' (kg=0) holds eid of slot eb+row
                if (r < 5 && eb + row < E) out[(size_t)erow * 5 + r] = acc2[reg];
            }

            if (!more) break;
            tile = ntile; s = sn; d = dn; e = en;
        }
    }
}

extern "C" void kernel_launch(void* const* d_in, const int* in_sizes, int n_in,
                              void* d_out, int out_size, void* d_ws, size_t ws_size,
                              hipStream_t stream)
{
    const float* x     = (const float*)d_in[0];
    const int*   ei    = (const int*)d_in[1];
    const float* eattr = (const float*)d_in[2];
    const float* W1    = (const float*)d_in[3];
    const float* b1    = (const float*)d_in[4];
    const float* W2    = (const float*)d_in[5];
    const float* b2    = (const float*)d_in[6];
    const float* Wc1   = (const float*)d_in[7];
    const float* bc1   = (const float*)d_in[8];
    const float* Wc2   = (const float*)d_in[9];
    const float* bc2   = (const float*)d_in[10];
    float* outp = (float*)d_out;

    const int N = in_sizes[0] / 32;
    const int E = in_sizes[1] / 2;

    // ---- carve workspace (~47 MB) ----
    size_t off = 0;
    char* base = (char*)d_ws;
    auto carve = [&](size_t bytes) -> void* {
        void* p = base + off;
        off += (bytes + 255) & ~(size_t)255;
        return p;
    };
    int*   degcnt = (int*)carve((size_t)2 * N * 4);
    int*   cursor = degcnt + N;
    float* dinv   = (float*)carve((size_t)N * 4);
    int*   rs     = (int*)carve((size_t)(N + 1) * 4);
    int*   bsum   = (int*)carve(512 * 4);
    int*   boff   = (int*)carve(512 * 4);
    int*   col    = (int*)carve((size_t)E * 4);
    int*   dstarr = (int*)carve((size_t)E * 4);
    int*   eid    = (int*)carve((size_t)E * 4);
    unsigned short* hsc  = (unsigned short*)carve((size_t)N * 64 * 2);
    unsigned short* h1   = (unsigned short*)carve((size_t)N * 64 * 2);
    unsigned short* h2bf = h1;   // alias: h1 dead after nodemm64 reads it
    short* Wc1T   = (short*)carve(9216 * 2);
    short* Wc2T   = (short*)carve(2048 * 2);
    short* W2T    = (short*)carve(4096 * 2);
    short* W1T    = (short*)carve(2048 * 2);
    (void)ws_size; (void)n_in; (void)out_size;

    const int NB = (N + 255) / 256;
    const int EB = (E + 255) / 256;
    const int NA = (N + 7) / 8;          // agg: 8 nodes/block
    const int NM = (N + 127) / 128;      // nodemm MFMA: 128 nodes/block
    const int NT = (E + 127) / 128;      // edge-MLP tiles
    const int MG = NT < 2048 ? NT : 2048;

    hipMemsetAsync(degcnt, 0, (size_t)2 * N * 4, stream);

    k_prep<<<68, 256, 0, stream>>>(Wc1, Wc2, W2, W1, Wc1T, Wc2T, W2T, W1T);
    k_hist<<<EB, 256, 0, stream>>>(ei, degcnt, E);
    k_dinv_bsum<<<NB, 256, 0, stream>>>(degcnt, dinv, N, bsum);
    k_boff<<<1, 512, 0, stream>>>(bsum, NB, boff);
    k_rowstart<<<NB, 256, 0, stream>>>(degcnt, boff, rs, N, E);
    k_scatter<<<EB, 256, 0, stream>>>(ei, rs, cursor, col, dstarr, eid, E);

    // layer 1
    k_nodemm32_mfma<<<NM, 256, 0, stream>>>(x, W1T, dinv, hsc, N);
    k_agg_bf<1><<<NA, 256, 0, stream>>>(hsc, dinv, rs, col, b1, h1, N);
    // layer 2
    k_nodemm64_mfma<<<NM, 256, 0, stream>>>(h1, W2T, dinv, hsc, N);
    k_agg_bf<0><<<NA, 256, 0, stream>>>(hsc, dinv, rs, col, b2, h2bf, N);
    // edge MLP (persistent blocks, CSR order)
    k_edge_mlp_mfma<<<MG, 256, 0, stream>>>(h2bf, eattr, col, dstarr, eid,
                                            Wc1T, bc1, Wc2T, bc2, outp, E, NT);
}